// Round 3
// baseline (154.175 us; speedup 1.0000x reference)
//
#include <hip/hip_runtime.h>

typedef __bf16 bf16;
typedef __bf16 bf16x8 __attribute__((ext_vector_type(8)));
typedef float  f32x4  __attribute__((ext_vector_type(4)));

#define MFMA(a, b, c) __builtin_amdgcn_mfma_f32_16x16x32_bf16((a), (b), (c), 0, 0, 0)

static constexpr int B_   = 2;
static constexpr int T_   = 2048;
static constexpr int D_   = 1024;
static constexpr int NH_  = 16;
static constexpr int HD_  = 64;
static constexpr int WIN_ = 256;
static constexpr int M_   = B_ * T_;          // 4096
static constexpr int NQKV = D_ + 2 * HD_;     // 1152

// softmax scale 1/sqrt(64) with log2(e) folded in: attention uses exp2 (raw
// v_exp_f32, no ln2 multiply per element)
static constexpr float QSCALE = 0.125f * 1.44269504088896f;

// async global->LDS, 16B per lane; global addr per-lane, LDS dst wave-uniform
// base + lane*16 [m97/m104-verified]
__device__ __forceinline__ void gld_lds16(const bf16* g, bf16* l) {
  __builtin_amdgcn_global_load_lds(
      (const __attribute__((address_space(1))) void*)g,
      (__attribute__((address_space(3))) void*)l, 16, 0, 0);
}

// ---------------------------------------------------------------------------
// Fused fp32->bf16 conversion of all 6 inputs. Wq/Wk/Wv -> Wqkv[1152][1024].
// ---------------------------------------------------------------------------
__global__ __launch_bounds__(256) void conv_all(
    const float* __restrict__ x,  const float* __restrict__ wq,
    const float* __restrict__ wk, const float* __restrict__ wv,
    const float* __restrict__ wf, const float* __restrict__ bv,
    bf16* __restrict__ xc, bf16* __restrict__ wqkv,
    bf16* __restrict__ wfc, bf16* __restrict__ bfc) {
  const long i = (long)(blockIdx.x * 256 + threadIdx.x) * 4;
  const float* src; bf16* dst; long off;
  if      (i < 4194304L) { src = x;  dst = xc;              off = 0; }
  else if (i < 5242880L) { src = wq; dst = wqkv;            off = 4194304L; }
  else if (i < 5308416L) { src = wk; dst = wqkv + 1048576L; off = 5242880L; }
  else if (i < 5373952L) { src = wv; dst = wqkv + 1114112L; off = 5308416L; }
  else if (i < 6422528L) { src = wf; dst = wfc;             off = 5373952L; }
  else if (i < 6423552L) { src = bv; dst = bfc;             off = 6422528L; }
  else return;
  const long j = i - off;
  const float4 v = *(const float4*)(src + j);
  bf16 o[4] = {(bf16)v.x, (bf16)v.y, (bf16)v.z, (bf16)v.w};
  *(uint2*)(dst + j) = *(const uint2*)o;
}

// ---------------------------------------------------------------------------
// GEMM, tile 128x128, BK=64, 2-phase double-buffer, 512 THREADS / 8 WAVES.
// R1 post-mortem: 4 waves at ~1 block/CU = 1 wave/SIMD -> nothing covers the
// barrier vmcnt(0) drain (m233: stage+vmcnt+barrier is the 2-phase critical
// path). m230's 682 TF 2-phase ran 8 waves in the same 1-block/CU regime —
// 2 waves/SIMD is the minimum for cross-wave MFMA/stage overlap. 8-phase is
// geometry-blocked (output 4096x1152 can't fill a 256²-tile grid).
// Wave grid 2x4: wave = 64 rows x 32 cols (acc 4x2); 4 gld_lds16/wave.
// C[M,N] = A[M,K] @ B[N,K]^T.
// EPI=1: QKV split (q scaled by QSCALE / k / vT transposed). EPI=2: fp32+bias.
// ---------------------------------------------------------------------------
template <int EPI>
__global__ __launch_bounds__(512) void gemm128x128(
    const bf16* __restrict__ A, const bf16* __restrict__ Bw,
    void* __restrict__ Cout, const bf16* __restrict__ bias,
    bf16* __restrict__ kb, bf16* __restrict__ vT, int N, int K) {
  __shared__ __align__(16) bf16 As[2][128 * 64];   // 2 x 16 KB
  __shared__ __align__(16) bf16 Bs[2][128 * 64];   // 2 x 16 KB

  const int tid  = threadIdx.x;
  const int w    = tid >> 6;        // 0..7
  const int lane = tid & 63;
  const int quad = lane >> 4;
  const int l16  = lane & 15;
  const int wm   = w & 1;           // row half (64 rows)
  const int wn   = w >> 1;          // col quarter (32 cols)
  const int m0   = blockIdx.x * 128;
  const int n0   = blockIdx.y * 128;
  const int lrow = lane >> 3;        // 0..7
  const int lcol = (lane & 7) * 8;   // 0..56

  f32x4 acc[4][2] = {};

  // 32 gld_lds16 insts: 16 for As (128 rows), 16 for Bs (128 rows); 4/wave
  auto stage = [&](int buf, int k0) {
#pragma unroll
    for (int t = 0; t < 4; ++t) {
      const int inst = w * 4 + t;  // wave-uniform
      if (inst < 16) {
        gld_lds16(&A[(size_t)(m0 + inst * 8 + lrow) * K + k0 + lcol],
                  &As[buf][inst * 512]);
      } else {
        const int bi = inst - 16;
        gld_lds16(&Bw[(size_t)(n0 + bi * 8 + lrow) * K + k0 + lcol],
                  &Bs[buf][bi * 512]);
      }
    }
  };

  auto compute = [&](int buf) {
#pragma unroll
    for (int kk = 0; kk < 64; kk += 32) {
      bf16x8 a[4], b[2];
#pragma unroll
      for (int i = 0; i < 4; ++i)
        a[i] = *(const bf16x8*)&As[buf][(wm * 64 + i * 16 + l16) * 64 + kk + quad * 8];
#pragma unroll
      for (int j = 0; j < 2; ++j)
        b[j] = *(const bf16x8*)&Bs[buf][(wn * 32 + j * 16 + l16) * 64 + kk + quad * 8];
#pragma unroll
      for (int i = 0; i < 4; ++i)
#pragma unroll
        for (int j = 0; j < 2; ++j) acc[i][j] = MFMA(a[i], b[j], acc[i][j]);
    }
  };

  // prologue: fill buf0, sync (vmcnt(0)+barrier inside __syncthreads)
  stage(0, 0);
  __syncthreads();
  int cur = 0;
  for (int k0 = 64; k0 < K; k0 += 64) {
    stage(cur ^ 1, k0);     // issue next-tile loads FIRST (overlap with MFMA)
    compute(cur);
    __syncthreads();        // drains vmcnt: next buf staged; all reads done
    cur ^= 1;
  }
  compute(cur);             // epilogue tile, no prefetch

  // epilogue: C/D layout col=l16, row=quad*4+r (m89-verified)
#pragma unroll
  for (int i = 0; i < 4; ++i) {
#pragma unroll
    for (int j = 0; j < 2; ++j) {
      const int col     = n0 + wn * 32 + j * 16 + l16;
      const int rowbase = m0 + wm * 64 + i * 16 + quad * 4;
      if (EPI == 1) {
        if (col < D_) {
          bf16* qb = (bf16*)Cout;
#pragma unroll
          for (int r = 0; r < 4; ++r)  // fold softmax scale * log2e into q
            qb[(size_t)(rowbase + r) * D_ + col] = (bf16)(acc[i][j][r] * QSCALE);
        } else if (col < D_ + HD_) {
#pragma unroll
          for (int r = 0; r < 4; ++r)
            kb[(size_t)(rowbase + r) * HD_ + (col - D_)] = (bf16)acc[i][j][r];
        } else {
          bf16 o[4] = {(bf16)acc[i][j][0], (bf16)acc[i][j][1],
                       (bf16)acc[i][j][2], (bf16)acc[i][j][3]};
          *(uint2*)&vT[(size_t)(col - D_ - HD_) * M_ + rowbase] = *(const uint2*)o;
        }
      } else {
        float* outp = (float*)Cout;
        const float bvv = (float)bias[col];
#pragma unroll
        for (int r = 0; r < 4; ++r)
          outp[(size_t)(rowbase + r) * D_ + col] = acc[i][j][r] + bvv;
      }
    }
  }
}

// ---------------------------------------------------------------------------
// Windowed attention (MQA), Q-tile = 128, q pre-scaled by QSCALE (log2-domain
// -> exp2 softmax). QK computed TRANSPOSED (A=K-frag, B=Q-frag -> C/D col=t,
// row=s). Q hoisted to registers (16 VGPR/wave); K/V double-buffered via
// global_load_lds with prefetch overlapped across the softmax phase.
// Un-normalized softmax (NaN-free); in-place q/o safe. UNCHANGED this round.
// ---------------------------------------------------------------------------
__global__ __launch_bounds__(256) void attn_win128(
    const bf16* __restrict__ q, const bf16* __restrict__ k,
    const bf16* __restrict__ vT, bf16* __restrict__ o) {
  __shared__ __align__(16) bf16 Ks[2][64 * 64];   // 16 KB
  __shared__ __align__(16) bf16 Vt[2][64 * 64];   // 16 KB [h][s]
  __shared__ __align__(16) bf16 Ps[128 * 72];     // 18 KB padded
  __shared__ float ls[4][32];                     // per-wave l[t] redistribute

  const int tid  = threadIdx.x;
  const int w    = tid >> 6;
  const int lane = tid & 63;
  const int quad = lane >> 4;
  const int l16  = lane & 15;
  const int lrow = lane >> 3;        // 0..7
  const int lcol = (lane & 7) * 8;   // 0..56

  const int t0 = blockIdx.x * 128;
  const int n  = blockIdx.y;
  const int b  = blockIdx.z;

  auto stageKV = [&](int st, int pb) {
#pragma unroll
    for (int t = 0; t < 2; ++t) {
      const int inst = w * 2 + t;
      gld_lds16(&k[((size_t)(b * T_ + st + inst * 8 + lrow)) * HD_ + lcol],
                &Ks[pb][inst * 512]);
      gld_lds16(&vT[(size_t)(inst * 8 + lrow) * M_ + b * T_ + st + lcol],
                &Vt[pb][inst * 512]);
    }
  };

  const int st_lo = (t0 - WIN_ > 0) ? t0 - WIN_ : 0;
  const int st_hi = (t0 + WIN_ + 64 < T_ - 64) ? t0 + WIN_ + 64 : T_ - 64;

  stageKV(st_lo, 0);
  int pb = 0;

  // Q-hoist: wave's B-fragments for both kk slices, direct from global.
  // row = t0 + w*32 + tt*16 + l16, k-elems = kq*32 + quad*8 .. +8
  bf16x8 qf[2][2];
#pragma unroll
  for (int tt = 0; tt < 2; ++tt)
#pragma unroll
    for (int kq = 0; kq < 2; ++kq)
      qf[tt][kq] = *(const bf16x8*)
          &q[((size_t)(b * T_ + t0 + w * 32 + tt * 16 + l16)) * D_ +
             n * HD_ + kq * 32 + quad * 8];

  f32x4 o_acc[2][4] = {};
  float l_part[2] = {0.0f, 0.0f};  // per-t partials, t = t0 + w*32 + tt*16 + l16

  for (int st = st_lo; st <= st_hi; st += 64) {
    __syncthreads();  // drains vmcnt: buf[pb] ready; prior PV done
    if (st + 64 <= st_hi) stageKV(st + 64, pb ^ 1);  // overlapped prefetch

    // S^T = K Q^T : MFMA(A=K-frag, B=Q-frag) -> C/D col=t, row=s
    f32x4 sacc[4][2] = {};  // [stile][tt]
#pragma unroll
    for (int kk = 0; kk < 64; kk += 32) {
      bf16x8 ak[4];
#pragma unroll
      for (int stile = 0; stile < 4; ++stile)
        ak[stile] = *(const bf16x8*)&Ks[pb][(stile * 16 + l16) * 64 + kk + quad * 8];
      __builtin_amdgcn_s_setprio(1);
#pragma unroll
      for (int stile = 0; stile < 4; ++stile)
#pragma unroll
        for (int tt = 0; tt < 2; ++tt)
          sacc[stile][tt] = MFMA(ak[stile], qf[tt][kk >> 5], sacc[stile][tt]);
      __builtin_amdgcn_s_setprio(0);
    }

    // softmax numerators (log2-domain -> exp2); lane holds col
    // t = w*32+tt*16+l16, rows s = stile*16+quad*4+r -> b64 stores into Ps
    const int off_t = st - t0;
    const bool need_mask =
        (off_t < w * 32 - (WIN_ - 31)) || (off_t > w * 32 + (WIN_ - 63));
    if (!need_mask) {
#pragma unroll
      for (int tt = 0; tt < 2; ++tt) {
#pragma unroll
        for (int stile = 0; stile < 4; ++stile) {
          bf16 pk[4];
          float psum = 0.0f;
#pragma unroll
          for (int r = 0; r < 4; ++r) {
            const float p =
                __builtin_amdgcn_exp2f(fminf(sacc[stile][tt][r], 43.28f));
            psum += p;
            pk[r] = (bf16)p;
          }
          l_part[tt] += psum;
          *(uint2*)&Ps[(w * 32 + tt * 16 + l16) * 72 + stile * 16 + quad * 4] =
              *(const uint2*)pk;
        }
      }
    } else {
#pragma unroll
      for (int tt = 0; tt < 2; ++tt) {
        const int t = t0 + w * 32 + tt * 16 + l16;
#pragma unroll
        for (int stile = 0; stile < 4; ++stile) {
          bf16 pk[4];
          float psum = 0.0f;
#pragma unroll
          for (int r = 0; r < 4; ++r) {
            const int s = st + stile * 16 + quad * 4 + r;
            const int d = t - s;
            const float p =
                (d > WIN_ || d < -WIN_)
                    ? 0.0f
                    : __builtin_amdgcn_exp2f(fminf(sacc[stile][tt][r], 43.28f));
            psum += p;
            pk[r] = (bf16)p;
          }
          l_part[tt] += psum;
          *(uint2*)&Ps[(w * 32 + tt * 16 + l16) * 72 + stile * 16 + quad * 4] =
              *(const uint2*)pk;
        }
      }
    }
    __syncthreads();  // Ps visible (prefetch drains here, overlapped)

    // O += P V  (A-frag: Ps rows t contiguous in s; B-frag: Vt rows h)
#pragma unroll
    for (int kk = 0; kk < 64; kk += 32) {
      bf16x8 ap[2];
#pragma unroll
      for (int rg = 0; rg < 2; ++rg)
        ap[rg] = *(const bf16x8*)&Ps[(w * 32 + rg * 16 + l16) * 72 + kk + quad * 8];
      __builtin_amdgcn_s_setprio(1);
#pragma unroll
      for (int nt = 0; nt < 4; ++nt) {
        bf16x8 bv = *(const bf16x8*)&Vt[pb][(nt * 16 + l16) * 64 + kk + quad * 8];
#pragma unroll
        for (int rg = 0; rg < 2; ++rg)
          o_acc[rg][nt] = MFMA(ap[rg], bv, o_acc[rg][nt]);
      }
      __builtin_amdgcn_s_setprio(0);
    }
    pb ^= 1;
  }

  // finalize l[t]: reduce per-t partials across the 4 quads, redistribute
#pragma unroll
  for (int tt = 0; tt < 2; ++tt) {
    l_part[tt] += __shfl_xor(l_part[tt], 16);
    l_part[tt] += __shfl_xor(l_part[tt], 32);
    if (quad == 0) ls[w][tt * 16 + l16] = l_part[tt];
  }
  __syncthreads();

#pragma unroll
  for (int rg = 0; rg < 2; ++rg) {
#pragma unroll
    for (int r = 0; r < 4; ++r) {
      const float lr = ls[w][rg * 16 + quad * 4 + r] + 1e-30f;
      const int t = t0 + w * 32 + rg * 16 + quad * 4 + r;
#pragma unroll
      for (int nt = 0; nt < 4; ++nt) {
        const int h = nt * 16 + l16;
        o[((size_t)(b * T_ + t)) * D_ + n * HD_ + h] =
            (bf16)(o_acc[rg][nt][r] / lr);
      }
    }
  }
}

// ---------------------------------------------------------------------------
extern "C" void kernel_launch(void* const* d_in, const int* in_sizes, int n_in,
                              void* d_out, int out_size, void* d_ws, size_t ws_size,
                              hipStream_t stream) {
  float* out = (float*)d_out;  // reference output dtype is float32

  bf16* xc   = (bf16*)d_ws;                   // 4096 x 1024
  bf16* wqkv = xc   + (size_t)M_ * D_;        // 1152 x 1024
  bf16* wfc  = wqkv + (size_t)NQKV * D_;      // 1024 x 1024
  bf16* bfc  = wfc  + (size_t)D_ * D_;        // 1024
  bf16* qb   = bfc  + D_;                     // 4096 x 1024 (attn out in-place)
  bf16* kb   = qb   + (size_t)M_ * D_;        // 4096 x 64
  bf16* vT   = kb   + (size_t)M_ * HD_;       // 64 x 4096 (transposed)

  dim3 blk(256);
  dim3 blkG(512);
  conv_all<<<dim3((6423552 / 4 + 255) / 256), blk, 0, stream>>>(
      (const float*)d_in[0], (const float*)d_in[1], (const float*)d_in[2],
      (const float*)d_in[3], (const float*)d_in[4], (const float*)d_in[5],
      xc, wqkv, wfc, bfc);

  gemm128x128<1><<<dim3(M_ / 128, NQKV / 128), blkG, 0, stream>>>(
      xc, wqkv, (void*)qb, nullptr, kb, vT, NQKV, D_);

  attn_win128<<<dim3(T_ / 128, NH_, B_), blk, 0, stream>>>(qb, kb, vT, qb);

  gemm128x128<2><<<dim3(M_ / 128, D_ / 128), blkG, 0, stream>>>(
      qb, wfc, (void*)out, bfc, nullptr, nullptr, D_, D_);
}

// Round 4
// 151.276 us; speedup vs baseline: 1.0192x; 1.0192x over previous
//
#include <hip/hip_runtime.h>

typedef __bf16 bf16;
typedef __bf16 bf16x8 __attribute__((ext_vector_type(8)));
typedef float  f32x4  __attribute__((ext_vector_type(4)));

#define MFMA(a, b, c) __builtin_amdgcn_mfma_f32_16x16x32_bf16((a), (b), (c), 0, 0, 0)

static constexpr int B_   = 2;
static constexpr int T_   = 2048;
static constexpr int D_   = 1024;
static constexpr int NH_  = 16;
static constexpr int HD_  = 64;
static constexpr int WIN_ = 256;
static constexpr int M_   = B_ * T_;          // 4096
static constexpr int NQKV = D_ + 2 * HD_;     // 1152

// softmax scale 1/sqrt(64) with log2(e) folded in: attention uses exp2 (raw
// v_exp_f32, no ln2 multiply per element)
static constexpr float QSCALE = 0.125f * 1.44269504088896f;

// async global->LDS, 16B per lane; global addr per-lane, LDS dst wave-uniform
// base + lane*16 [m97/m104-verified]
__device__ __forceinline__ void gld_lds16(const bf16* g, bf16* l) {
  __builtin_amdgcn_global_load_lds(
      (const __attribute__((address_space(1))) void*)g,
      (__attribute__((address_space(3))) void*)l, 16, 0, 0);
}

// ---------------------------------------------------------------------------
// Fused fp32->bf16 conversion of all 6 inputs. Wq/Wk/Wv -> Wqkv[1152][1024].
// ---------------------------------------------------------------------------
__global__ __launch_bounds__(256) void conv_all(
    const float* __restrict__ x,  const float* __restrict__ wq,
    const float* __restrict__ wk, const float* __restrict__ wv,
    const float* __restrict__ wf, const float* __restrict__ bv,
    bf16* __restrict__ xc, bf16* __restrict__ wqkv,
    bf16* __restrict__ wfc, bf16* __restrict__ bfc) {
  const long i = (long)(blockIdx.x * 256 + threadIdx.x) * 4;
  const float* src; bf16* dst; long off;
  if      (i < 4194304L) { src = x;  dst = xc;              off = 0; }
  else if (i < 5242880L) { src = wq; dst = wqkv;            off = 4194304L; }
  else if (i < 5308416L) { src = wk; dst = wqkv + 1048576L; off = 5242880L; }
  else if (i < 5373952L) { src = wv; dst = wqkv + 1114112L; off = 5308416L; }
  else if (i < 6422528L) { src = wf; dst = wfc;             off = 5373952L; }
  else if (i < 6423552L) { src = bv; dst = bfc;             off = 6422528L; }
  else return;
  const long j = i - off;
  const float4 v = *(const float4*)(src + j);
  bf16 o[4] = {(bf16)v.x, (bf16)v.y, (bf16)v.z, (bf16)v.w};
  *(uint2*)(dst + j) = *(const uint2*)o;
}

// ---------------------------------------------------------------------------
// GEMM, tile 128x128, BK=64, 2-phase double-buffer, 4 waves (R2 config — the
// best of 4 measured in-CU variants; wave/buffer scheduling is NOT the lever).
// NEW: XCD-STRIPED 1-D GRID. Fetch arithmetic: with default round-robin, A is
// re-fetched once per n-panel (9x8.4MB) and B once per m-panel (32x2.4MB) —
// ~150MB through L3/HBM per GEMM, ~50µs of tile re-fetch at 1 block/CU that
// no in-CU pipelining hides. Mapping: xcd = bid&7 (hw round-robin across 8
// XCDs), each XCD owns a FIXED stripe of 4 m-tiles (512 A-rows = 1MB,
// resident in its 4MB L2 across all n-panels) and walks n-panels with the
// current 0.26MB B-panel hot. A fetched ~once per XCD instead of 9x.
//   mt = (bid&7)*4 + ((bid>>3)&3),  nt = bid>>5   (bijective for 288/256).
// C[M,N] = A[M,K] @ B[N,K]^T.
// EPI=1: QKV split (q scaled by QSCALE / k / vT transposed). EPI=2: fp32+bias.
// ---------------------------------------------------------------------------
template <int EPI>
__global__ __launch_bounds__(256) void gemm128x128(
    const bf16* __restrict__ A, const bf16* __restrict__ Bw,
    void* __restrict__ Cout, const bf16* __restrict__ bias,
    bf16* __restrict__ kb, bf16* __restrict__ vT, int N, int K) {
  __shared__ __align__(16) bf16 As[2][128 * 64];   // 2 x 16 KB
  __shared__ __align__(16) bf16 Bs[2][128 * 64];   // 2 x 16 KB

  const int tid  = threadIdx.x;
  const int w    = tid >> 6;
  const int lane = tid & 63;
  const int quad = lane >> 4;
  const int l16  = lane & 15;
  const int wm   = w & 1;   // row half (64 rows)
  const int wn   = w >> 1;  // col half (64 cols)

  // XCD-striped block mapping (1-D grid, grids are multiples of 32)
  const int bid = blockIdx.x;
  const int m0  = ((bid & 7) * 4 + ((bid >> 3) & 3)) * 128;
  const int n0  = (bid >> 5) * 128;

  const int lrow = lane >> 3;        // 0..7
  const int lcol = (lane & 7) * 8;   // 0..56

  f32x4 acc[4][4] = {};

  // 32 gld_lds16 insts: 16 for As (128 rows), 16 for Bs (128 rows); 8/wave
  auto stage = [&](int buf, int k0) {
#pragma unroll
    for (int t = 0; t < 8; ++t) {
      const int inst = w * 8 + t;  // wave-uniform
      if (inst < 16) {
        gld_lds16(&A[(size_t)(m0 + inst * 8 + lrow) * K + k0 + lcol],
                  &As[buf][inst * 512]);
      } else {
        const int bi = inst - 16;
        gld_lds16(&Bw[(size_t)(n0 + bi * 8 + lrow) * K + k0 + lcol],
                  &Bs[buf][bi * 512]);
      }
    }
  };

  auto compute = [&](int buf) {
#pragma unroll
    for (int kk = 0; kk < 64; kk += 32) {
      bf16x8 a[4], b[4];
#pragma unroll
      for (int i = 0; i < 4; ++i)
        a[i] = *(const bf16x8*)&As[buf][(wm * 64 + i * 16 + l16) * 64 + kk + quad * 8];
#pragma unroll
      for (int j = 0; j < 4; ++j)
        b[j] = *(const bf16x8*)&Bs[buf][(wn * 64 + j * 16 + l16) * 64 + kk + quad * 8];
#pragma unroll
      for (int i = 0; i < 4; ++i)
#pragma unroll
        for (int j = 0; j < 4; ++j) acc[i][j] = MFMA(a[i], b[j], acc[i][j]);
    }
  };

  // prologue: fill buf0, sync (vmcnt(0)+barrier inside __syncthreads)
  stage(0, 0);
  __syncthreads();
  int cur = 0;
  for (int k0 = 64; k0 < K; k0 += 64) {
    stage(cur ^ 1, k0);     // issue next-tile loads FIRST (overlap with MFMA)
    compute(cur);
    __syncthreads();        // drains vmcnt: next buf staged; all reads done
    cur ^= 1;
  }
  compute(cur);             // epilogue tile, no prefetch

  // epilogue: C/D layout col=l16, row=quad*4+r (m89-verified)
#pragma unroll
  for (int i = 0; i < 4; ++i) {
#pragma unroll
    for (int j = 0; j < 4; ++j) {
      const int col     = n0 + wn * 64 + j * 16 + l16;
      const int rowbase = m0 + wm * 64 + i * 16 + quad * 4;
      if (EPI == 1) {
        if (col < D_) {
          bf16* qb = (bf16*)Cout;
#pragma unroll
          for (int r = 0; r < 4; ++r)  // fold softmax scale * log2e into q
            qb[(size_t)(rowbase + r) * D_ + col] = (bf16)(acc[i][j][r] * QSCALE);
        } else if (col < D_ + HD_) {
#pragma unroll
          for (int r = 0; r < 4; ++r)
            kb[(size_t)(rowbase + r) * HD_ + (col - D_)] = (bf16)acc[i][j][r];
        } else {
          bf16 o[4] = {(bf16)acc[i][j][0], (bf16)acc[i][j][1],
                       (bf16)acc[i][j][2], (bf16)acc[i][j][3]};
          *(uint2*)&vT[(size_t)(col - D_ - HD_) * M_ + rowbase] = *(const uint2*)o;
        }
      } else {
        float* outp = (float*)Cout;
        const float bvv = (float)bias[col];
#pragma unroll
        for (int r = 0; r < 4; ++r)
          outp[(size_t)(rowbase + r) * D_ + col] = acc[i][j][r] + bvv;
      }
    }
  }
}

// ---------------------------------------------------------------------------
// Windowed attention (MQA), Q-tile = 128, q pre-scaled by QSCALE (log2-domain
// -> exp2 softmax). QK computed TRANSPOSED (A=K-frag, B=Q-frag -> C/D col=t,
// row=s). Q hoisted to registers (16 VGPR/wave); K/V double-buffered via
// global_load_lds with prefetch overlapped across the softmax phase.
// Un-normalized softmax (NaN-free); in-place q/o safe. UNCHANGED this round.
// ---------------------------------------------------------------------------
__global__ __launch_bounds__(256) void attn_win128(
    const bf16* __restrict__ q, const bf16* __restrict__ k,
    const bf16* __restrict__ vT, bf16* __restrict__ o) {
  __shared__ __align__(16) bf16 Ks[2][64 * 64];   // 16 KB
  __shared__ __align__(16) bf16 Vt[2][64 * 64];   // 16 KB [h][s]
  __shared__ __align__(16) bf16 Ps[128 * 72];     // 18 KB padded
  __shared__ float ls[4][32];                     // per-wave l[t] redistribute

  const int tid  = threadIdx.x;
  const int w    = tid >> 6;
  const int lane = tid & 63;
  const int quad = lane >> 4;
  const int l16  = lane & 15;
  const int lrow = lane >> 3;        // 0..7
  const int lcol = (lane & 7) * 8;   // 0..56

  const int t0 = blockIdx.x * 128;
  const int n  = blockIdx.y;
  const int b  = blockIdx.z;

  auto stageKV = [&](int st, int pb) {
#pragma unroll
    for (int t = 0; t < 2; ++t) {
      const int inst = w * 2 + t;
      gld_lds16(&k[((size_t)(b * T_ + st + inst * 8 + lrow)) * HD_ + lcol],
                &Ks[pb][inst * 512]);
      gld_lds16(&vT[(size_t)(inst * 8 + lrow) * M_ + b * T_ + st + lcol],
                &Vt[pb][inst * 512]);
    }
  };

  const int st_lo = (t0 - WIN_ > 0) ? t0 - WIN_ : 0;
  const int st_hi = (t0 + WIN_ + 64 < T_ - 64) ? t0 + WIN_ + 64 : T_ - 64;

  stageKV(st_lo, 0);
  int pb = 0;

  // Q-hoist: wave's B-fragments for both kk slices, direct from global.
  // row = t0 + w*32 + tt*16 + l16, k-elems = kq*32 + quad*8 .. +8
  bf16x8 qf[2][2];
#pragma unroll
  for (int tt = 0; tt < 2; ++tt)
#pragma unroll
    for (int kq = 0; kq < 2; ++kq)
      qf[tt][kq] = *(const bf16x8*)
          &q[((size_t)(b * T_ + t0 + w * 32 + tt * 16 + l16)) * D_ +
             n * HD_ + kq * 32 + quad * 8];

  f32x4 o_acc[2][4] = {};
  float l_part[2] = {0.0f, 0.0f};  // per-t partials, t = t0 + w*32 + tt*16 + l16

  for (int st = st_lo; st <= st_hi; st += 64) {
    __syncthreads();  // drains vmcnt: buf[pb] ready; prior PV done
    if (st + 64 <= st_hi) stageKV(st + 64, pb ^ 1);  // overlapped prefetch

    // S^T = K Q^T : MFMA(A=K-frag, B=Q-frag) -> C/D col=t, row=s
    f32x4 sacc[4][2] = {};  // [stile][tt]
#pragma unroll
    for (int kk = 0; kk < 64; kk += 32) {
      bf16x8 ak[4];
#pragma unroll
      for (int stile = 0; stile < 4; ++stile)
        ak[stile] = *(const bf16x8*)&Ks[pb][(stile * 16 + l16) * 64 + kk + quad * 8];
      __builtin_amdgcn_s_setprio(1);
#pragma unroll
      for (int stile = 0; stile < 4; ++stile)
#pragma unroll
        for (int tt = 0; tt < 2; ++tt)
          sacc[stile][tt] = MFMA(ak[stile], qf[tt][kk >> 5], sacc[stile][tt]);
      __builtin_amdgcn_s_setprio(0);
    }

    // softmax numerators (log2-domain -> exp2); lane holds col
    // t = w*32+tt*16+l16, rows s = stile*16+quad*4+r -> b64 stores into Ps
    const int off_t = st - t0;
    const bool need_mask =
        (off_t < w * 32 - (WIN_ - 31)) || (off_t > w * 32 + (WIN_ - 63));
    if (!need_mask) {
#pragma unroll
      for (int tt = 0; tt < 2; ++tt) {
#pragma unroll
        for (int stile = 0; stile < 4; ++stile) {
          bf16 pk[4];
          float psum = 0.0f;
#pragma unroll
          for (int r = 0; r < 4; ++r) {
            const float p =
                __builtin_amdgcn_exp2f(fminf(sacc[stile][tt][r], 43.28f));
            psum += p;
            pk[r] = (bf16)p;
          }
          l_part[tt] += psum;
          *(uint2*)&Ps[(w * 32 + tt * 16 + l16) * 72 + stile * 16 + quad * 4] =
              *(const uint2*)pk;
        }
      }
    } else {
#pragma unroll
      for (int tt = 0; tt < 2; ++tt) {
        const int t = t0 + w * 32 + tt * 16 + l16;
#pragma unroll
        for (int stile = 0; stile < 4; ++stile) {
          bf16 pk[4];
          float psum = 0.0f;
#pragma unroll
          for (int r = 0; r < 4; ++r) {
            const int s = st + stile * 16 + quad * 4 + r;
            const int d = t - s;
            const float p =
                (d > WIN_ || d < -WIN_)
                    ? 0.0f
                    : __builtin_amdgcn_exp2f(fminf(sacc[stile][tt][r], 43.28f));
            psum += p;
            pk[r] = (bf16)p;
          }
          l_part[tt] += psum;
          *(uint2*)&Ps[(w * 32 + tt * 16 + l16) * 72 + stile * 16 + quad * 4] =
              *(const uint2*)pk;
        }
      }
    }
    __syncthreads();  // Ps visible (prefetch drains here, overlapped)

    // O += P V  (A-frag: Ps rows t contiguous in s; B-frag: Vt rows h)
#pragma unroll
    for (int kk = 0; kk < 64; kk += 32) {
      bf16x8 ap[2];
#pragma unroll
      for (int rg = 0; rg < 2; ++rg)
        ap[rg] = *(const bf16x8*)&Ps[(w * 32 + rg * 16 + l16) * 72 + kk + quad * 8];
      __builtin_amdgcn_s_setprio(1);
#pragma unroll
      for (int nt = 0; nt < 4; ++nt) {
        bf16x8 bv = *(const bf16x8*)&Vt[pb][(nt * 16 + l16) * 64 + kk + quad * 8];
#pragma unroll
        for (int rg = 0; rg < 2; ++rg)
          o_acc[rg][nt] = MFMA(ap[rg], bv, o_acc[rg][nt]);
      }
      __builtin_amdgcn_s_setprio(0);
    }
    pb ^= 1;
  }

  // finalize l[t]: reduce per-t partials across the 4 quads, redistribute
#pragma unroll
  for (int tt = 0; tt < 2; ++tt) {
    l_part[tt] += __shfl_xor(l_part[tt], 16);
    l_part[tt] += __shfl_xor(l_part[tt], 32);
    if (quad == 0) ls[w][tt * 16 + l16] = l_part[tt];
  }
  __syncthreads();

#pragma unroll
  for (int rg = 0; rg < 2; ++rg) {
#pragma unroll
    for (int r = 0; r < 4; ++r) {
      const float lr = ls[w][rg * 16 + quad * 4 + r] + 1e-30f;
      const int t = t0 + w * 32 + rg * 16 + quad * 4 + r;
#pragma unroll
      for (int nt = 0; nt < 4; ++nt) {
        const int h = nt * 16 + l16;
        o[((size_t)(b * T_ + t)) * D_ + n * HD_ + h] =
            (bf16)(o_acc[rg][nt][r] / lr);
      }
    }
  }
}

// ---------------------------------------------------------------------------
extern "C" void kernel_launch(void* const* d_in, const int* in_sizes, int n_in,
                              void* d_out, int out_size, void* d_ws, size_t ws_size,
                              hipStream_t stream) {
  float* out = (float*)d_out;  // reference output dtype is float32

  bf16* xc   = (bf16*)d_ws;                   // 4096 x 1024
  bf16* wqkv = xc   + (size_t)M_ * D_;        // 1152 x 1024
  bf16* wfc  = wqkv + (size_t)NQKV * D_;      // 1024 x 1024
  bf16* bfc  = wfc  + (size_t)D_ * D_;        // 1024
  bf16* qb   = bfc  + D_;                     // 4096 x 1024 (attn out in-place)
  bf16* kb   = qb   + (size_t)M_ * D_;        // 4096 x 64
  bf16* vT   = kb   + (size_t)M_ * HD_;       // 64 x 4096 (transposed)

  dim3 blk(256);
  conv_all<<<dim3((6423552 / 4 + 255) / 256), blk, 0, stream>>>(
      (const float*)d_in[0], (const float*)d_in[1], (const float*)d_in[2],
      (const float*)d_in[3], (const float*)d_in[4], (const float*)d_in[5],
      xc, wqkv, wfc, bfc);

  // 1-D XCD-striped grids: 8 xcds * 4 m-tiles * NT n-tiles
  gemm128x128<1><<<dim3(8 * 4 * (NQKV / 128)), blk, 0, stream>>>(
      xc, wqkv, (void*)qb, nullptr, kb, vT, NQKV, D_);

  attn_win128<<<dim3(T_ / 128, NH_, B_), blk, 0, stream>>>(qb, kb, vT, qb);

  gemm128x128<2><<<dim3(8 * 4 * (D_ / 128)), blk, 0, stream>>>(
      qb, wfc, (void*)out, bfc, nullptr, nullptr, D_, D_);
}

// Round 5
// 137.796 us; speedup vs baseline: 1.1189x; 1.0978x over previous
//
#include <hip/hip_runtime.h>

typedef __bf16 bf16;
typedef __bf16 bf16x8 __attribute__((ext_vector_type(8)));
typedef float  f32x4  __attribute__((ext_vector_type(4)));

#define MFMA(a, b, c) __builtin_amdgcn_mfma_f32_16x16x32_bf16((a), (b), (c), 0, 0, 0)

static constexpr int B_   = 2;
static constexpr int T_   = 2048;
static constexpr int D_   = 1024;
static constexpr int NH_  = 16;
static constexpr int HD_  = 64;
static constexpr int WIN_ = 256;
static constexpr int M_   = B_ * T_;          // 4096
static constexpr int NQKV = D_ + 2 * HD_;     // 1152

// softmax scale 1/sqrt(64) with log2(e) folded in: attention uses exp2
static constexpr float QSCALE = 0.125f * 1.44269504088896f;

// async global->LDS, 16B per lane; global addr per-lane, LDS dst wave-uniform
// base + lane*16 [m97/m104-verified]
__device__ __forceinline__ void gld_lds16(const bf16* g, bf16* l) {
  __builtin_amdgcn_global_load_lds(
      (const __attribute__((address_space(1))) void*)g,
      (__attribute__((address_space(3))) void*)l, 16, 0, 0);
}

// ---------------------------------------------------------------------------
// BANK-CONFLICT SWIZZLE (rule #21: both-sides-or-neither, m201/m173 pattern).
// All staged tiles are [R][64] bf16 (128 B rows): a fragment read at
// row=..+l16, fixed col-block puts all 16 lanes of a quad on the SAME 4
// banks (16-way conflict; §6 G4's measured 52%-of-attn-time case).
// Fix: LDS dst stays LINEAR (gld_lds16 requirement); the global SOURCE
// column is pre-swizzled per-lane, and every LDS read applies the same XOR:
//   write: lane stages global col ((lane&7)^(lane>>3))*8  (row&7 == lane>>3)
//   read : col' = col ^ ((row&7)*8)                       (row&7 == l16&7)
// After swizzle each quad spans all 32 banks (2-way residual = free, m136).
// ---------------------------------------------------------------------------

// ---------------------------------------------------------------------------
// Fused fp32->bf16 conversion of all 6 inputs. Wq/Wk/Wv -> Wqkv[1152][1024].
// ---------------------------------------------------------------------------
__global__ __launch_bounds__(256) void conv_all(
    const float* __restrict__ x,  const float* __restrict__ wq,
    const float* __restrict__ wk, const float* __restrict__ wv,
    const float* __restrict__ wf, const float* __restrict__ bv,
    bf16* __restrict__ xc, bf16* __restrict__ wqkv,
    bf16* __restrict__ wfc, bf16* __restrict__ bfc) {
  const long i = (long)(blockIdx.x * 256 + threadIdx.x) * 4;
  const float* src; bf16* dst; long off;
  if      (i < 4194304L) { src = x;  dst = xc;              off = 0; }
  else if (i < 5242880L) { src = wq; dst = wqkv;            off = 4194304L; }
  else if (i < 5308416L) { src = wk; dst = wqkv + 1048576L; off = 5242880L; }
  else if (i < 5373952L) { src = wv; dst = wqkv + 1114112L; off = 5308416L; }
  else if (i < 6422528L) { src = wf; dst = wfc;             off = 5373952L; }
  else if (i < 6423552L) { src = bv; dst = bfc;             off = 6422528L; }
  else return;
  const long j = i - off;
  const float4 v = *(const float4*)(src + j);
  bf16 o[4] = {(bf16)v.x, (bf16)v.y, (bf16)v.z, (bf16)v.w};
  *(uint2*)(dst + j) = *(const uint2*)o;
}

// ---------------------------------------------------------------------------
// GEMM, tile 128x128, BK=64, 2-phase double-buffer, 4 waves (R2 config, best
// measured) + XOR bank-conflict swizzle on As/Bs (see above).
// C[M,N] = A[M,K] @ B[N,K]^T.
// EPI=1: QKV split (q scaled by QSCALE / k / vT transposed). EPI=2: fp32+bias.
// ---------------------------------------------------------------------------
template <int EPI>
__global__ __launch_bounds__(256) void gemm128x128(
    const bf16* __restrict__ A, const bf16* __restrict__ Bw,
    void* __restrict__ Cout, const bf16* __restrict__ bias,
    bf16* __restrict__ kb, bf16* __restrict__ vT, int N, int K) {
  __shared__ __align__(16) bf16 As[2][128 * 64];   // 2 x 16 KB
  __shared__ __align__(16) bf16 Bs[2][128 * 64];   // 2 x 16 KB

  const int tid  = threadIdx.x;
  const int w    = tid >> 6;
  const int lane = tid & 63;
  const int quad = lane >> 4;
  const int l16  = lane & 15;
  const int wm   = w & 1;   // row half (64 rows)
  const int wn   = w >> 1;  // col half (64 cols)
  const int m0   = blockIdx.x * 128;
  const int n0   = blockIdx.y * 128;
  const int lrow = lane >> 3;                       // 0..7 (== row&7 staged)
  const int scol = ((lane & 7) ^ lrow) * 8;         // pre-swizzled source col
  const int rx   = (l16 & 7) * 8;                   // read-side XOR term

  f32x4 acc[4][4] = {};

  // 32 gld_lds16 insts: 16 for As (128 rows), 16 for Bs (128 rows); 8/wave
  auto stage = [&](int buf, int k0) {
#pragma unroll
    for (int t = 0; t < 8; ++t) {
      const int inst = w * 8 + t;  // wave-uniform
      if (inst < 16) {
        gld_lds16(&A[(size_t)(m0 + inst * 8 + lrow) * K + k0 + scol],
                  &As[buf][inst * 512]);
      } else {
        const int bi = inst - 16;
        gld_lds16(&Bw[(size_t)(n0 + bi * 8 + lrow) * K + k0 + scol],
                  &Bs[buf][bi * 512]);
      }
    }
  };

  auto compute = [&](int buf) {
#pragma unroll
    for (int kk = 0; kk < 64; kk += 32) {
      const int c = (kk + quad * 8) ^ rx;  // swizzled column (row&7 == l16&7)
      bf16x8 a[4], b[4];
#pragma unroll
      for (int i = 0; i < 4; ++i)
        a[i] = *(const bf16x8*)&As[buf][(wm * 64 + i * 16 + l16) * 64 + c];
#pragma unroll
      for (int j = 0; j < 4; ++j)
        b[j] = *(const bf16x8*)&Bs[buf][(wn * 64 + j * 16 + l16) * 64 + c];
#pragma unroll
      for (int i = 0; i < 4; ++i)
#pragma unroll
        for (int j = 0; j < 4; ++j) acc[i][j] = MFMA(a[i], b[j], acc[i][j]);
    }
  };

  // prologue: fill buf0, sync (vmcnt(0)+barrier inside __syncthreads)
  stage(0, 0);
  __syncthreads();
  int cur = 0;
  for (int k0 = 64; k0 < K; k0 += 64) {
    stage(cur ^ 1, k0);     // issue next-tile loads FIRST (overlap with MFMA)
    compute(cur);
    __syncthreads();        // drains vmcnt: next buf staged; all reads done
    cur ^= 1;
  }
  compute(cur);             // epilogue tile, no prefetch

  // epilogue: C/D layout col=l16, row=quad*4+r (m89-verified)
#pragma unroll
  for (int i = 0; i < 4; ++i) {
#pragma unroll
    for (int j = 0; j < 4; ++j) {
      const int col     = n0 + wn * 64 + j * 16 + l16;
      const int rowbase = m0 + wm * 64 + i * 16 + quad * 4;
      if (EPI == 1) {
        if (col < D_) {
          bf16* qb = (bf16*)Cout;
#pragma unroll
          for (int r = 0; r < 4; ++r)  // fold softmax scale * log2e into q
            qb[(size_t)(rowbase + r) * D_ + col] = (bf16)(acc[i][j][r] * QSCALE);
        } else if (col < D_ + HD_) {
#pragma unroll
          for (int r = 0; r < 4; ++r)
            kb[(size_t)(rowbase + r) * HD_ + (col - D_)] = (bf16)acc[i][j][r];
        } else {
          bf16 o[4] = {(bf16)acc[i][j][0], (bf16)acc[i][j][1],
                       (bf16)acc[i][j][2], (bf16)acc[i][j][3]};
          *(uint2*)&vT[(size_t)(col - D_ - HD_) * M_ + rowbase] = *(const uint2*)o;
        }
      } else {
        float* outp = (float*)Cout;
        const float bvv = (float)bias[col];
#pragma unroll
        for (int r = 0; r < 4; ++r)
          outp[(size_t)(rowbase + r) * D_ + col] = acc[i][j][r] + bvv;
      }
    }
  }
}

// ---------------------------------------------------------------------------
// Windowed attention (MQA), Q-tile = 128, q pre-scaled by QSCALE (exp2
// softmax). QK computed TRANSPOSED (A=K-frag, B=Q-frag -> C/D col=t, row=s).
// Q hoisted to registers; K/V double-buffered via global_load_lds.
// NEW: XOR bank-conflict swizzle on Ks/Vt (20 conflicted ds_read_b128 per
// wave per s-step were the exposed critical path here — staging is tiny so
// nothing hides them, unlike the GEMM's T2-null regime). Ps already 72-padded.
// Un-normalized softmax (NaN-free); in-place q/o safe.
// ---------------------------------------------------------------------------
__global__ __launch_bounds__(256) void attn_win128(
    const bf16* __restrict__ q, const bf16* __restrict__ k,
    const bf16* __restrict__ vT, bf16* __restrict__ o) {
  __shared__ __align__(16) bf16 Ks[2][64 * 64];   // 16 KB
  __shared__ __align__(16) bf16 Vt[2][64 * 64];   // 16 KB [h][s]
  __shared__ __align__(16) bf16 Ps[128 * 72];     // 18 KB padded
  __shared__ float ls[4][32];                     // per-wave l[t] redistribute

  const int tid  = threadIdx.x;
  const int w    = tid >> 6;
  const int lane = tid & 63;
  const int quad = lane >> 4;
  const int l16  = lane & 15;
  const int lrow = lane >> 3;                     // 0..7 (== row&7 staged)
  const int scol = ((lane & 7) ^ lrow) * 8;       // pre-swizzled source col
  const int rx   = (l16 & 7) * 8;                 // read-side XOR term

  const int t0 = blockIdx.x * 128;
  const int n  = blockIdx.y;
  const int b  = blockIdx.z;

  auto stageKV = [&](int st, int pb) {
#pragma unroll
    for (int t = 0; t < 2; ++t) {
      const int inst = w * 2 + t;
      gld_lds16(&k[((size_t)(b * T_ + st + inst * 8 + lrow)) * HD_ + scol],
                &Ks[pb][inst * 512]);
      gld_lds16(&vT[(size_t)(inst * 8 + lrow) * M_ + b * T_ + st + scol],
                &Vt[pb][inst * 512]);
    }
  };

  const int st_lo = (t0 - WIN_ > 0) ? t0 - WIN_ : 0;
  const int st_hi = (t0 + WIN_ + 64 < T_ - 64) ? t0 + WIN_ + 64 : T_ - 64;

  stageKV(st_lo, 0);
  int pb = 0;

  // Q-hoist: wave's B-fragments for both kk slices, direct from global.
  bf16x8 qf[2][2];
#pragma unroll
  for (int tt = 0; tt < 2; ++tt)
#pragma unroll
    for (int kq = 0; kq < 2; ++kq)
      qf[tt][kq] = *(const bf16x8*)
          &q[((size_t)(b * T_ + t0 + w * 32 + tt * 16 + l16)) * D_ +
             n * HD_ + kq * 32 + quad * 8];

  f32x4 o_acc[2][4] = {};
  float l_part[2] = {0.0f, 0.0f};  // per-t partials, t = t0 + w*32 + tt*16 + l16

  for (int st = st_lo; st <= st_hi; st += 64) {
    __syncthreads();  // drains vmcnt: buf[pb] ready; prior PV done
    if (st + 64 <= st_hi) stageKV(st + 64, pb ^ 1);  // overlapped prefetch

    // S^T = K Q^T : MFMA(A=K-frag, B=Q-frag) -> C/D col=t, row=s
    f32x4 sacc[4][2] = {};  // [stile][tt]
#pragma unroll
    for (int kk = 0; kk < 64; kk += 32) {
      const int c = (kk + quad * 8) ^ rx;  // swizzled col (K rows: row&7==l16&7)
      bf16x8 ak[4];
#pragma unroll
      for (int stile = 0; stile < 4; ++stile)
        ak[stile] = *(const bf16x8*)&Ks[pb][(stile * 16 + l16) * 64 + c];
      __builtin_amdgcn_s_setprio(1);
#pragma unroll
      for (int stile = 0; stile < 4; ++stile)
#pragma unroll
        for (int tt = 0; tt < 2; ++tt)
          sacc[stile][tt] = MFMA(ak[stile], qf[tt][kk >> 5], sacc[stile][tt]);
      __builtin_amdgcn_s_setprio(0);
    }

    // softmax numerators (exp2); lane holds col t = w*32+tt*16+l16,
    // rows s = stile*16+quad*4+r -> b64 stores into Ps
    const int off_t = st - t0;
    const bool need_mask =
        (off_t < w * 32 - (WIN_ - 31)) || (off_t > w * 32 + (WIN_ - 63));
    if (!need_mask) {
#pragma unroll
      for (int tt = 0; tt < 2; ++tt) {
#pragma unroll
        for (int stile = 0; stile < 4; ++stile) {
          bf16 pk[4];
          float psum = 0.0f;
#pragma unroll
          for (int r = 0; r < 4; ++r) {
            const float p =
                __builtin_amdgcn_exp2f(fminf(sacc[stile][tt][r], 43.28f));
            psum += p;
            pk[r] = (bf16)p;
          }
          l_part[tt] += psum;
          *(uint2*)&Ps[(w * 32 + tt * 16 + l16) * 72 + stile * 16 + quad * 4] =
              *(const uint2*)pk;
        }
      }
    } else {
#pragma unroll
      for (int tt = 0; tt < 2; ++tt) {
        const int t = t0 + w * 32 + tt * 16 + l16;
#pragma unroll
        for (int stile = 0; stile < 4; ++stile) {
          bf16 pk[4];
          float psum = 0.0f;
#pragma unroll
          for (int r = 0; r < 4; ++r) {
            const int s = st + stile * 16 + quad * 4 + r;
            const int d = t - s;
            const float p =
                (d > WIN_ || d < -WIN_)
                    ? 0.0f
                    : __builtin_amdgcn_exp2f(fminf(sacc[stile][tt][r], 43.28f));
            psum += p;
            pk[r] = (bf16)p;
          }
          l_part[tt] += psum;
          *(uint2*)&Ps[(w * 32 + tt * 16 + l16) * 72 + stile * 16 + quad * 4] =
              *(const uint2*)pk;
        }
      }
    }
    __syncthreads();  // Ps visible (prefetch drains here, overlapped)

    // O += P V  (A-frag: Ps rows t contiguous in s; B-frag: Vt rows h)
#pragma unroll
    for (int kk = 0; kk < 64; kk += 32) {
      const int c = (kk + quad * 8) ^ rx;  // swizzled col for Vt
      bf16x8 ap[2];
#pragma unroll
      for (int rg = 0; rg < 2; ++rg)
        ap[rg] = *(const bf16x8*)&Ps[(w * 32 + rg * 16 + l16) * 72 + kk + quad * 8];
      __builtin_amdgcn_s_setprio(1);
#pragma unroll
      for (int nt = 0; nt < 4; ++nt) {
        bf16x8 bv = *(const bf16x8*)&Vt[pb][(nt * 16 + l16) * 64 + c];
#pragma unroll
        for (int rg = 0; rg < 2; ++rg)
          o_acc[rg][nt] = MFMA(ap[rg], bv, o_acc[rg][nt]);
      }
      __builtin_amdgcn_s_setprio(0);
    }
    pb ^= 1;
  }

  // finalize l[t]: reduce per-t partials across the 4 quads, redistribute
#pragma unroll
  for (int tt = 0; tt < 2; ++tt) {
    l_part[tt] += __shfl_xor(l_part[tt], 16);
    l_part[tt] += __shfl_xor(l_part[tt], 32);
    if (quad == 0) ls[w][tt * 16 + l16] = l_part[tt];
  }
  __syncthreads();

#pragma unroll
  for (int rg = 0; rg < 2; ++rg) {
#pragma unroll
    for (int r = 0; r < 4; ++r) {
      const float lr = ls[w][rg * 16 + quad * 4 + r] + 1e-30f;
      const int t = t0 + w * 32 + rg * 16 + quad * 4 + r;
#pragma unroll
      for (int nt = 0; nt < 4; ++nt) {
        const int h = nt * 16 + l16;
        o[((size_t)(b * T_ + t)) * D_ + n * HD_ + h] =
            (bf16)(o_acc[rg][nt][r] / lr);
      }
    }
  }
}

// ---------------------------------------------------------------------------
extern "C" void kernel_launch(void* const* d_in, const int* in_sizes, int n_in,
                              void* d_out, int out_size, void* d_ws, size_t ws_size,
                              hipStream_t stream) {
  float* out = (float*)d_out;  // reference output dtype is float32

  bf16* xc   = (bf16*)d_ws;                   // 4096 x 1024
  bf16* wqkv = xc   + (size_t)M_ * D_;        // 1152 x 1024
  bf16* wfc  = wqkv + (size_t)NQKV * D_;      // 1024 x 1024
  bf16* bfc  = wfc  + (size_t)D_ * D_;        // 1024
  bf16* qb   = bfc  + D_;                     // 4096 x 1024 (attn out in-place)
  bf16* kb   = qb   + (size_t)M_ * D_;        // 4096 x 64
  bf16* vT   = kb   + (size_t)M_ * HD_;       // 64 x 4096 (transposed)

  dim3 blk(256);
  conv_all<<<dim3((6423552 / 4 + 255) / 256), blk, 0, stream>>>(
      (const float*)d_in[0], (const float*)d_in[1], (const float*)d_in[2],
      (const float*)d_in[3], (const float*)d_in[4], (const float*)d_in[5],
      xc, wqkv, wfc, bfc);

  gemm128x128<1><<<dim3(M_ / 128, NQKV / 128), blk, 0, stream>>>(
      xc, wqkv, (void*)qb, nullptr, kb, vT, NQKV, D_);

  attn_win128<<<dim3(T_ / 128, NH_, B_), blk, 0, stream>>>(qb, kb, vT, qb);

  gemm128x128<2><<<dim3(M_ / 128, D_ / 128), blk, 0, stream>>>(
      qb, wfc, (void*)out, bfc, nullptr, nullptr, D_, D_);
}